// Round 17
// baseline (509.041 us; speedup 1.0000x reference)
//
#include <hip/hip_runtime.h>
#include <hip/hip_bf16.h>

#define N_NODES 50000
#define N_EDGES 640000

typedef __attribute__((ext_vector_type(8))) _Float16 f16x8;
typedef __attribute__((ext_vector_type(4))) float f32x4;

static __device__ __forceinline__ float sgpr_f(const float* p) {
    return __uint_as_float(__builtin_amdgcn_readfirstlane(__float_as_uint(*p)));
}

// ---- tiny pre-pass: W2/b2 f32 -> f16 table in d_ws (17 tiles x 512) ----
// layout: w2h[(c*16 + o)*32 + k], c=16 is the b2 bias tile.
__global__ __launch_bounds__(256)
void w2_convert_kernel(const float* __restrict__ W2,
                       const float* __restrict__ b2,
                       _Float16* __restrict__ w2h)
{
    const int i = blockIdx.x * 256 + threadIdx.x;   // 0 .. 17*512-1
    if (i >= 17 * 512) return;
    const int c   = i >> 9;
    const int rem = i & 511;
    w2h[i] = (_Float16)(c < 16 ? W2[c * 512 + rem] : b2[rem]);
}

__global__ __launch_bounds__(256)
void edge_hyper_kernel(const float* __restrict__ x,
                       const int* __restrict__ ei,      // int32 [2][E]
                       const float* __restrict__ ev,
                       const float* __restrict__ nrm,
                       const float* __restrict__ W1,
                       const float* __restrict__ b1,
                       const _Float16* __restrict__ w2h, // preconverted f16 tiles
                       float* __restrict__ accum,        // TRANSPOSED [16][N_NODES]
                       int ngroups)
{
    const int tid  = threadIdx.x;
    const int l    = tid & 63;
    const int r    = l & 15;         // A-row edge-in-group / D col o
    const int half = l >> 4;         // 0..3 -> k-range half*8..half*8+7

    // ---- persistent B fragments (17 tiles x 16B/lane) ----
    f16x8 bfrag[17];
    #pragma unroll
    for (int c = 0; c < 17; ++c) {
        bfrag[c] = *reinterpret_cast<const f16x8*>(
            w2h + ((c * 16 + r) * 32 + half * 8));
    }

    // ---- W1/b1 pinned to SGPRs ----
    float w1c0[16], w1c1[16], w1c2[16], b1s[16];
    #pragma unroll
    for (int c = 0; c < 16; ++c) {
        w1c0[c] = sgpr_f(W1 + c);
        w1c1[c] = sgpr_f(W1 + 16 + c);
        w1c2[c] = sgpr_f(W1 + 32 + c);
        b1s[c]  = sgpr_f(b1 + c);
    }

    const int wv = tid >> 6;
    int g = blockIdx.x * 4 + wv;        // nw=8192 <= ngroups: always has work
    const int nw = gridDim.x * 4;
    const int eisel = (half >= 2 ? N_EDGES : 0);

    // per-lane accumulator row base (o = r fixed per lane)
    float* arow = accum + (size_t)r * N_NODES;

    // ---- pipeline prologue (R15 structure) ----
    float  e0_c, e1_c, e2_c;
    float4 xa_c, xb_c, nr_c;
    int4   dst_c;
    int    idx_p1;
    float  e0_p1, e1_p1, e2_p1;
    float4 nr_p1;
    int4   dst_p1;
    {
        const int e0 = g * 16;
        const int idx0 = ei[eisel + e0 + r];
        const float* evp = ev + (size_t)(e0 + r) * 3;
        e0_c = evp[0]; e1_c = evp[1]; e2_c = evp[2];
        nr_c  = *reinterpret_cast<const float4*>(nrm + e0 + half * 4);
        dst_c = *reinterpret_cast<const int4*>(ei + N_EDGES + e0 + half * 4);
        const float4* xr = reinterpret_cast<const float4*>(
            x + (size_t)idx0 * 16 + (half & 1) * 8);
        xa_c = xr[0];
        xb_c = xr[1];
    }
    {
        const int gp1 = (g + nw < ngroups) ? g + nw : g;
        const int e0p = gp1 * 16;
        idx_p1 = ei[eisel + e0p + r];
        const float* evp = ev + (size_t)(e0p + r) * 3;
        e0_p1 = evp[0]; e1_p1 = evp[1]; e2_p1 = evp[2];
        nr_p1  = *reinterpret_cast<const float4*>(nrm + e0p + half * 4);
        dst_p1 = *reinterpret_cast<const int4*>(ei + N_EDGES + e0p + half * 4);
    }

    while (g < ngroups) {
        // ---- (1) x-gather for g+nw from RESIDENT idx_p1 (issued first) ----
        const float4* xr1 = reinterpret_cast<const float4*>(
            x + (size_t)idx_p1 * 16 + (half & 1) * 8);
        const float4 xa_p1 = xr1[0];
        const float4 xb_p1 = xr1[1];

        // ---- (2) scalar loads for g+2nw (idx/ev/nr/dst) ----
        const int gp2v = g + 2 * nw;
        const int gp2  = (gp2v < ngroups) ? gp2v : g;    // clamp: reload current
        const int e0p2 = gp2 * 16;
        const int idx_p2 = ei[eisel + e0p2 + r];
        const float* evp2 = ev + (size_t)(e0p2 + r) * 3;
        const float e0_p2 = evp2[0], e1_p2 = evp2[1], e2_p2 = evp2[2];
        const float4 nr_p2  = *reinterpret_cast<const float4*>(nrm + e0p2 + half * 4);
        const int4   dst_p2 = *reinterpret_cast<const int4*>(ei + N_EDGES + e0p2 + half * 4);

        // ---- (3) xe -> f16 fragment ----
        f16x8 xef;
        xef[0] = (_Float16)xa_c.x; xef[1] = (_Float16)xa_c.y;
        xef[2] = (_Float16)xa_c.z; xef[3] = (_Float16)xa_c.w;
        xef[4] = (_Float16)xb_c.x; xef[5] = (_Float16)xb_c.y;
        xef[6] = (_Float16)xb_c.z; xef[7] = (_Float16)xb_c.w;

        // ---- (4) bias tile (c=16): acc = xe @ b2^T ----
        f32x4 accA = __builtin_amdgcn_mfma_f32_16x16x32_f16(
            xef, bfrag[16], (f32x4){0.f, 0.f, 0.f, 0.f}, 0, 0, 0);
        f32x4 accB = (f32x4){0.f, 0.f, 0.f, 0.f};

        // ---- (5) 16 c-tiles: h inline, A = h*xe via packed f16 muls ----
        #pragma unroll
        for (int c = 0; c < 16; ++c) {
            float hc = fmaf(e2_c, w1c2[c],
                       fmaf(e1_c, w1c1[c],
                       fmaf(e0_c, w1c0[c], b1s[c])));
            hc = fmaxf(hc, 0.0f);
            const _Float16 hf = (_Float16)hc;
            f16x8 hv;
            #pragma unroll
            for (int j = 0; j < 8; ++j) hv[j] = hf;
            const f16x8 yf = xef * hv;          // 4x v_pk_mul_f16
            if (c & 1)
                accB = __builtin_amdgcn_mfma_f32_16x16x32_f16(yf, bfrag[c], accB, 0, 0, 0);
            else
                accA = __builtin_amdgcn_mfma_f32_16x16x32_f16(yf, bfrag[c], accA, 0, 0, 0);
        }

        // ---- (6) epilogue: tanh, norm scale, TRANSPOSED scatter-add ----
        // atomics from one edge-quad now hit 16 DIFFERENT 64B lines
        // (accum[o][node], o-rows 200KB apart) -> no per-line serialization.
        const float nrv[4] = {nr_c.x, nr_c.y, nr_c.z, nr_c.w};
        const int   dsv[4] = {dst_c.x, dst_c.y, dst_c.z, dst_c.w};
        #pragma unroll
        for (int q = 0; q < 4; ++q) {
            const float sv = accA[q] + accB[q];
            const float t  = __expf(-2.0f * fabsf(sv));
            const float th = copysignf((1.0f - t) * __builtin_amdgcn_rcpf(1.0f + t), sv);
            atomicAdd(arow + dsv[q], th * nrv[q]);
        }

        // ---- (7) rotate pipeline state ----
        xa_c = xa_p1; xb_c = xb_p1;
        e0_c = e0_p1; e1_c = e1_p1; e2_c = e2_p1;
        nr_c = nr_p1; dst_c = dst_p1;
        idx_p1 = idx_p2;
        e0_p1 = e0_p2; e1_p1 = e1_p2; e2_p1 = e2_p2;
        nr_p1 = nr_p2; dst_p1 = dst_p2;
        g += nw;
    }
}

// ---- finalize: transpose accum[16][N_NODES] -> out[N_NODES][16] ----
// reads coalesced per o-row (consecutive nodes), writes coalesced float4 x4.
__global__ __launch_bounds__(256)
void finalize_kernel(const float* __restrict__ accum,
                     float4* __restrict__ out4)
{
    const int node = blockIdx.x * 256 + threadIdx.x;
    if (node >= N_NODES) return;
    float v[16];
    #pragma unroll
    for (int o = 0; o < 16; ++o)
        v[o] = accum[(size_t)o * N_NODES + node];
    float4* dst = out4 + (size_t)node * 4;
    dst[0] = make_float4(v[0],  v[1],  v[2],  v[3]);
    dst[1] = make_float4(v[4],  v[5],  v[6],  v[7]);
    dst[2] = make_float4(v[8],  v[9],  v[10], v[11]);
    dst[3] = make_float4(v[12], v[13], v[14], v[15]);
}

extern "C" void kernel_launch(void* const* d_in, const int* in_sizes, int n_in,
                              void* d_out, int out_size, void* d_ws, size_t ws_size,
                              hipStream_t stream) {
    const float* x   = (const float*)d_in[0];
    const int*   ei  = (const int*)d_in[1];
    const float* ev  = (const float*)d_in[2];
    const float* nrm = (const float*)d_in[3];
    const float* W1  = (const float*)d_in[4];
    const float* b1  = (const float*)d_in[5];
    const float* W2  = (const float*)d_in[6];
    const float* b2  = (const float*)d_in[7];
    float* out = (float*)d_out;

    // ws layout: [0, 17408) f16 W2 table | [32768, 32768+3.2MB) f32 accum^T
    _Float16* w2h   = (_Float16*)d_ws;
    float*    accum = (float*)((char*)d_ws + 32768);
    const size_t accum_bytes = (size_t)N_NODES * 16 * sizeof(float);  // 3.2 MB

    hipMemsetAsync(accum, 0, accum_bytes, stream);
    hipLaunchKernelGGL(w2_convert_kernel, dim3(34), dim3(256), 0, stream,
                       W2, b2, w2h);

    const int ngroups = N_EDGES / 16;   // 40000, exact
    hipLaunchKernelGGL(edge_hyper_kernel, dim3(2048), dim3(256), 0, stream,
                       x, ei, ev, nrm, W1, b1, w2h, accum, ngroups);

    hipLaunchKernelGGL(finalize_kernel, dim3((N_NODES + 255) / 256), dim3(256),
                       0, stream, accum, (float4*)out);
}

// Round 18
// 60.852 us; speedup vs baseline: 8.3653x; 8.3653x over previous
//
#include <hip/hip_runtime.h>
#include <hip/hip_bf16.h>

#define N_NODES 50000
#define N_EDGES 640000

typedef __attribute__((ext_vector_type(8))) _Float16 f16x8;
typedef __attribute__((ext_vector_type(4))) float f32x4;

static __device__ __forceinline__ float sgpr_f(const float* p) {
    return __uint_as_float(__builtin_amdgcn_readfirstlane(__float_as_uint(*p)));
}

__global__ __launch_bounds__(256)
void edge_hyper_kernel(const float* __restrict__ x,
                       const int* __restrict__ ei,      // int32 [2][E]
                       const float* __restrict__ ev,
                       const float* __restrict__ nrm,
                       const float* __restrict__ W1,
                       const float* __restrict__ b1,
                       const float* __restrict__ W2,
                       const float* __restrict__ b2,
                       float* __restrict__ out,
                       int ngroups)
{
    const int tid  = threadIdx.x;
    const int l    = tid & 63;
    const int r    = l & 15;         // A-row edge-in-group / D col o
    const int half = l >> 4;         // 0..3 -> k-range half*8..half*8+7

    // ---- persistent B fragments: converted f32->f16 in-kernel, once per
    // wave (one-time prologue; removes the separate convert dispatch) ----
    f16x8 bfrag[17];
    #pragma unroll
    for (int c = 0; c < 17; ++c) {
        const float* p = (c < 16) ? (W2 + c * 512 + r * 32 + half * 8)
                                  : (b2 + r * 32 + half * 8);
        const float4 a = *reinterpret_cast<const float4*>(p);
        const float4 b = *reinterpret_cast<const float4*>(p + 4);
        f16x8 t;
        t[0] = (_Float16)a.x; t[1] = (_Float16)a.y;
        t[2] = (_Float16)a.z; t[3] = (_Float16)a.w;
        t[4] = (_Float16)b.x; t[5] = (_Float16)b.y;
        t[6] = (_Float16)b.z; t[7] = (_Float16)b.w;
        bfrag[c] = t;
    }

    // ---- W1/b1 pinned to SGPRs ----
    float w1c0[16], w1c1[16], w1c2[16], b1s[16];
    #pragma unroll
    for (int c = 0; c < 16; ++c) {
        w1c0[c] = sgpr_f(W1 + c);
        w1c1[c] = sgpr_f(W1 + 16 + c);
        w1c2[c] = sgpr_f(W1 + 32 + c);
        b1s[c]  = sgpr_f(b1 + c);
    }

    const int wv = tid >> 6;
    int g = blockIdx.x * 4 + wv;        // nw=8192 <= ngroups: always has work
    const int nw = gridDim.x * 4;
    const int eisel = (half >= 2 ? N_EDGES : 0);

    // ---- pipeline prologue (R15 structure) ----
    float  e0_c, e1_c, e2_c;
    float4 xa_c, xb_c, nr_c;
    int4   dst_c;
    int    idx_p1;
    float  e0_p1, e1_p1, e2_p1;
    float4 nr_p1;
    int4   dst_p1;
    {
        const int e0 = g * 16;
        const int idx0 = ei[eisel + e0 + r];
        const float* evp = ev + (size_t)(e0 + r) * 3;
        e0_c = evp[0]; e1_c = evp[1]; e2_c = evp[2];
        nr_c  = *reinterpret_cast<const float4*>(nrm + e0 + half * 4);
        dst_c = *reinterpret_cast<const int4*>(ei + N_EDGES + e0 + half * 4);
        const float4* xr = reinterpret_cast<const float4*>(
            x + (size_t)idx0 * 16 + (half & 1) * 8);
        xa_c = xr[0];
        xb_c = xr[1];
    }
    {
        const int gp1 = (g + nw < ngroups) ? g + nw : g;
        const int e0p = gp1 * 16;
        idx_p1 = ei[eisel + e0p + r];
        const float* evp = ev + (size_t)(e0p + r) * 3;
        e0_p1 = evp[0]; e1_p1 = evp[1]; e2_p1 = evp[2];
        nr_p1  = *reinterpret_cast<const float4*>(nrm + e0p + half * 4);
        dst_p1 = *reinterpret_cast<const int4*>(ei + N_EDGES + e0p + half * 4);
    }

    while (g < ngroups) {
        // ---- (1) x-gather for g+nw from RESIDENT idx_p1 (issued first,
        //          before this iteration's atomics) ----
        const float4* xr1 = reinterpret_cast<const float4*>(
            x + (size_t)idx_p1 * 16 + (half & 1) * 8);
        const float4 xa_p1 = xr1[0];
        const float4 xb_p1 = xr1[1];

        // ---- (2) scalar loads for g+2nw (idx/ev/nr/dst) ----
        const int gp2v = g + 2 * nw;
        const int gp2  = (gp2v < ngroups) ? gp2v : g;    // clamp: reload current
        const int e0p2 = gp2 * 16;
        const int idx_p2 = ei[eisel + e0p2 + r];
        const float* evp2 = ev + (size_t)(e0p2 + r) * 3;
        const float e0_p2 = evp2[0], e1_p2 = evp2[1], e2_p2 = evp2[2];
        const float4 nr_p2  = *reinterpret_cast<const float4*>(nrm + e0p2 + half * 4);
        const int4   dst_p2 = *reinterpret_cast<const int4*>(ei + N_EDGES + e0p2 + half * 4);

        // ---- (3) xe -> f16 fragment (all _c state resident, no waits) ----
        f16x8 xef;
        xef[0] = (_Float16)xa_c.x; xef[1] = (_Float16)xa_c.y;
        xef[2] = (_Float16)xa_c.z; xef[3] = (_Float16)xa_c.w;
        xef[4] = (_Float16)xb_c.x; xef[5] = (_Float16)xb_c.y;
        xef[6] = (_Float16)xb_c.z; xef[7] = (_Float16)xb_c.w;

        // ---- (4) bias tile (c=16): acc = xe @ b2^T ----
        f32x4 accA = __builtin_amdgcn_mfma_f32_16x16x32_f16(
            xef, bfrag[16], (f32x4){0.f, 0.f, 0.f, 0.f}, 0, 0, 0);
        f32x4 accB = (f32x4){0.f, 0.f, 0.f, 0.f};

        // ---- (5) 16 c-tiles: h inline, A = h*xe via packed f16 muls ----
        #pragma unroll
        for (int c = 0; c < 16; ++c) {
            float hc = fmaf(e2_c, w1c2[c],
                       fmaf(e1_c, w1c1[c],
                       fmaf(e0_c, w1c0[c], b1s[c])));
            hc = fmaxf(hc, 0.0f);
            const _Float16 hf = (_Float16)hc;
            f16x8 hv;
            #pragma unroll
            for (int j = 0; j < 8; ++j) hv[j] = hf;
            const f16x8 yf = xef * hv;          // 4x v_pk_mul_f16
            if (c & 1)
                accB = __builtin_amdgcn_mfma_f32_16x16x32_f16(yf, bfrag[c], accB, 0, 0, 0);
            else
                accA = __builtin_amdgcn_mfma_f32_16x16x32_f16(yf, bfrag[c], accA, 0, 0, 0);
        }

        // ---- (6) epilogue: tanh, norm scale, f32 scatter-add (merged-line
        //          clustering is GOOD: 16 same-line RMWs merge in L2, R17) ----
        // D layout (m89-verified, dtype-independent): col=l&15 (=o=r), row=half*4+q
        const float nrv[4] = {nr_c.x, nr_c.y, nr_c.z, nr_c.w};
        const int   dsv[4] = {dst_c.x, dst_c.y, dst_c.z, dst_c.w};
        #pragma unroll
        for (int q = 0; q < 4; ++q) {
            const float sv = accA[q] + accB[q];
            const float t  = __expf(-2.0f * fabsf(sv));
            const float th = copysignf((1.0f - t) * __builtin_amdgcn_rcpf(1.0f + t), sv);
            atomicAdd(out + (size_t)dsv[q] * 16 + r, th * nrv[q]);
        }

        // ---- (7) rotate pipeline state ----
        xa_c = xa_p1; xb_c = xb_p1;
        e0_c = e0_p1; e1_c = e1_p1; e2_c = e2_p1;
        nr_c = nr_p1; dst_c = dst_p1;
        idx_p1 = idx_p2;
        e0_p1 = e0_p2; e1_p1 = e1_p2; e2_p1 = e2_p2;
        nr_p1 = nr_p2; dst_p1 = dst_p2;
        g += nw;
    }
}

extern "C" void kernel_launch(void* const* d_in, const int* in_sizes, int n_in,
                              void* d_out, int out_size, void* d_ws, size_t ws_size,
                              hipStream_t stream) {
    const float* x   = (const float*)d_in[0];
    const int*   ei  = (const int*)d_in[1];
    const float* ev  = (const float*)d_in[2];
    const float* nrm = (const float*)d_in[3];
    const float* W1  = (const float*)d_in[4];
    const float* b1  = (const float*)d_in[5];
    const float* W2  = (const float*)d_in[6];
    const float* b2  = (const float*)d_in[7];
    float* out = (float*)d_out;

    hipMemsetAsync(out, 0, (size_t)out_size * sizeof(float), stream);

    const int ngroups = N_EDGES / 16;   // 40000, exact
    hipLaunchKernelGGL(edge_hyper_kernel, dim3(2048), dim3(256), 0, stream,
                       x, ei, ev, nrm, W1, b1, W2, b2, out, ngroups);
}

// Round 19
// 49.788 us; speedup vs baseline: 10.2243x; 1.2222x over previous
//
#include <hip/hip_runtime.h>
#include <hip/hip_bf16.h>

#define N_NODES 50000
#define N_EDGES 640000

typedef __attribute__((ext_vector_type(8))) _Float16 f16x8;
typedef __attribute__((ext_vector_type(4))) float f32x4;

static __device__ __forceinline__ float sgpr_f(const float* p) {
    return __uint_as_float(__builtin_amdgcn_readfirstlane(__float_as_uint(*p)));
}

// ---- tiny pre-pass: W2/b2 f32 -> f16 table in d_ws (17 tiles x 512) ----
// layout: w2h[(c*16 + o)*32 + k], c=16 is the b2 bias tile.
__global__ __launch_bounds__(256)
void w2_convert_kernel(const float* __restrict__ W2,
                       const float* __restrict__ b2,
                       _Float16* __restrict__ w2h)
{
    const int i = blockIdx.x * 256 + threadIdx.x;   // 0 .. 17*512-1
    if (i >= 17 * 512) return;
    const int c   = i >> 9;
    const int rem = i & 511;
    w2h[i] = (_Float16)(c < 16 ? W2[c * 512 + rem] : b2[rem]);
}

__global__ __launch_bounds__(256)
void edge_hyper_kernel(const float* __restrict__ x,
                       const int* __restrict__ ei,      // int32 [2][E]
                       const float* __restrict__ ev,
                       const float* __restrict__ nrm,
                       const float* __restrict__ W1,
                       const float* __restrict__ b1,
                       const _Float16* __restrict__ w2h, // preconverted f16 tiles
                       float* __restrict__ out,
                       int ngroups)
{
    const int tid  = threadIdx.x;
    const int l    = tid & 63;
    const int r    = l & 15;         // A-row edge-in-group / D col o
    const int half = l >> 4;         // 0..3 -> k-range half*8..half*8+7

    // ---- persistent B fragments in registers: 17 tiles x 16B/lane (L1-hot) ----
    f16x8 bfrag[17];
    #pragma unroll
    for (int c = 0; c < 17; ++c) {
        bfrag[c] = *reinterpret_cast<const f16x8*>(
            w2h + ((c * 16 + r) * 32 + half * 8));
    }

    // ---- W1/b1 pinned to SGPRs ----
    float w1c0[16], w1c1[16], w1c2[16], b1s[16];
    #pragma unroll
    for (int c = 0; c < 16; ++c) {
        w1c0[c] = sgpr_f(W1 + c);
        w1c1[c] = sgpr_f(W1 + 16 + c);
        w1c2[c] = sgpr_f(W1 + 32 + c);
        b1s[c]  = sgpr_f(b1 + c);
    }

    const int wv = tid >> 6;
    int g = blockIdx.x * 4 + wv;        // nw=8192 <= ngroups: always has work
    const int nw = gridDim.x * 4;
    const int eisel = (half >= 2 ? N_EDGES : 0);

    // ---- pipeline prologue ----
    // group g: EVERYTHING resident (incl. x, nr, dst).
    // group g+nw: scalars resident (idx, ev, nr, dst); x gathered in-loop.
    float  e0_c, e1_c, e2_c;
    float4 xa_c, xb_c, nr_c;
    int4   dst_c;
    int    idx_p1;
    float  e0_p1, e1_p1, e2_p1;
    float4 nr_p1;
    int4   dst_p1;
    {
        const int e0 = g * 16;
        const int idx0 = ei[eisel + e0 + r];
        const float* evp = ev + (size_t)(e0 + r) * 3;
        e0_c = evp[0]; e1_c = evp[1]; e2_c = evp[2];
        nr_c  = *reinterpret_cast<const float4*>(nrm + e0 + half * 4);
        dst_c = *reinterpret_cast<const int4*>(ei + N_EDGES + e0 + half * 4);
        const float4* xr = reinterpret_cast<const float4*>(
            x + (size_t)idx0 * 16 + (half & 1) * 8);
        xa_c = xr[0];
        xb_c = xr[1];
    }
    {
        const int gp1 = (g + nw < ngroups) ? g + nw : g;
        const int e0p = gp1 * 16;
        idx_p1 = ei[eisel + e0p + r];
        const float* evp = ev + (size_t)(e0p + r) * 3;
        e0_p1 = evp[0]; e1_p1 = evp[1]; e2_p1 = evp[2];
        nr_p1  = *reinterpret_cast<const float4*>(nrm + e0p + half * 4);
        dst_p1 = *reinterpret_cast<const int4*>(ei + N_EDGES + e0p + half * 4);
    }

    while (g < ngroups) {
        // ---- (1) x-gather for g+nw from RESIDENT idx_p1 (issued FIRST,
        //          before this iteration's atomics -> consumable next iter
        //          with vmcnt(N>=4), atomics left outstanding) ----
        const float4* xr1 = reinterpret_cast<const float4*>(
            x + (size_t)idx_p1 * 16 + (half & 1) * 8);
        const float4 xa_p1 = xr1[0];
        const float4 xb_p1 = xr1[1];

        // ---- (2) scalar loads for g+2nw (idx/ev/nr/dst) ----
        const int gp2v = g + 2 * nw;
        const int gp2  = (gp2v < ngroups) ? gp2v : g;    // clamp: reload current
        const int e0p2 = gp2 * 16;
        const int idx_p2 = ei[eisel + e0p2 + r];
        const float* evp2 = ev + (size_t)(e0p2 + r) * 3;
        const float e0_p2 = evp2[0], e1_p2 = evp2[1], e2_p2 = evp2[2];
        const float4 nr_p2  = *reinterpret_cast<const float4*>(nrm + e0p2 + half * 4);
        const int4   dst_p2 = *reinterpret_cast<const int4*>(ei + N_EDGES + e0p2 + half * 4);

        // ---- (3) xe -> f16 fragment (all _c state resident, no waits) ----
        f16x8 xef;
        xef[0] = (_Float16)xa_c.x; xef[1] = (_Float16)xa_c.y;
        xef[2] = (_Float16)xa_c.z; xef[3] = (_Float16)xa_c.w;
        xef[4] = (_Float16)xb_c.x; xef[5] = (_Float16)xb_c.y;
        xef[6] = (_Float16)xb_c.z; xef[7] = (_Float16)xb_c.w;

        // ---- (4) bias tile (c=16): acc = xe @ b2^T ----
        f32x4 accA = __builtin_amdgcn_mfma_f32_16x16x32_f16(
            xef, bfrag[16], (f32x4){0.f, 0.f, 0.f, 0.f}, 0, 0, 0);
        f32x4 accB = (f32x4){0.f, 0.f, 0.f, 0.f};

        // ---- (5) 16 c-tiles: h inline, A = h*xe via packed f16 muls ----
        #pragma unroll
        for (int c = 0; c < 16; ++c) {
            float hc = fmaf(e2_c, w1c2[c],
                       fmaf(e1_c, w1c1[c],
                       fmaf(e0_c, w1c0[c], b1s[c])));
            hc = fmaxf(hc, 0.0f);
            const _Float16 hf = (_Float16)hc;
            f16x8 hv;
            #pragma unroll
            for (int j = 0; j < 8; ++j) hv[j] = hf;
            const f16x8 yf = xef * hv;          // 4x v_pk_mul_f16
            if (c & 1)
                accB = __builtin_amdgcn_mfma_f32_16x16x32_f16(yf, bfrag[c], accB, 0, 0, 0);
            else
                accA = __builtin_amdgcn_mfma_f32_16x16x32_f16(yf, bfrag[c], accA, 0, 0, 0);
        }

        // ---- (6) epilogue: tanh, norm scale, f32 scatter-add.
        //          nr_c/dst_c were loaded LAST iteration, before the previous
        //          atomics -> no wait here drains any atomic. ----
        // D layout (m89-verified, dtype-independent): col=l&15 (=o=r), row=half*4+q
        const float nrv[4] = {nr_c.x, nr_c.y, nr_c.z, nr_c.w};
        const int   dsv[4] = {dst_c.x, dst_c.y, dst_c.z, dst_c.w};
        #pragma unroll
        for (int q = 0; q < 4; ++q) {
            const float sv = accA[q] + accB[q];
            const float t  = __expf(-2.0f * fabsf(sv));
            const float th = copysignf((1.0f - t) * __builtin_amdgcn_rcpf(1.0f + t), sv);
            atomicAdd(out + (size_t)dsv[q] * 16 + r, th * nrv[q]);
        }

        // ---- (7) rotate pipeline state ----
        xa_c = xa_p1; xb_c = xb_p1;
        e0_c = e0_p1; e1_c = e1_p1; e2_c = e2_p1;
        nr_c = nr_p1; dst_c = dst_p1;
        idx_p1 = idx_p2;
        e0_p1 = e0_p2; e1_p1 = e1_p2; e2_p1 = e2_p2;
        nr_p1 = nr_p2; dst_p1 = dst_p2;
        g += nw;
    }
}

extern "C" void kernel_launch(void* const* d_in, const int* in_sizes, int n_in,
                              void* d_out, int out_size, void* d_ws, size_t ws_size,
                              hipStream_t stream) {
    const float* x   = (const float*)d_in[0];
    const int*   ei  = (const int*)d_in[1];
    const float* ev  = (const float*)d_in[2];
    const float* nrm = (const float*)d_in[3];
    const float* W1  = (const float*)d_in[4];
    const float* b1  = (const float*)d_in[5];
    const float* W2  = (const float*)d_in[6];
    const float* b2  = (const float*)d_in[7];
    float* out = (float*)d_out;
    _Float16* w2h = (_Float16*)d_ws;     // 17*512*2 = 17408 B

    hipMemsetAsync(out, 0, (size_t)out_size * sizeof(float), stream);

    hipLaunchKernelGGL(w2_convert_kernel, dim3(34), dim3(256), 0, stream,
                       W2, b2, w2h);

    const int ngroups = N_EDGES / 16;   // 40000, exact
    hipLaunchKernelGGL(edge_hyper_kernel, dim3(2048), dim3(256), 0, stream,
                       x, ei, ev, nrm, W1, b1, w2h, out, ngroups);
}